// Round 4
// baseline (339.932 us; speedup 1.0000x reference)
//
#include <hip/hip_runtime.h>
#include <cstdint>
#include <math.h>

// Problem constants (from reference)
#define GRID_W 96
#define GRID_L 96
#define GRID_H 48
#define NVOX (GRID_W * GRID_L * GRID_H)   // 442368
#define VOXEL_SIZE 0.05f
#define MIN_PTS 10
#define BATCH 4
#define CHANS 16
#define NPTS (480 * 640)                  // 307200 points per batch
#define TOTPTS (BATCH * NPTS)             // 1228800
#define TOTVOX (BATCH * NVOX)             // 1769472

// Scan geometry: 864 blocks x 256 threads x 8 elems = 1769472 exactly.
#define SCAN_BLKS 864
#define SCAN_TPB 256
#define SCAN_EPT 8
#define SCAN_CHUNK (SCAN_TPB * SCAN_EPT)  // 2048

#define ROWW 8   // uint words per bf16 row (16 channels x 2B = 32B)

// Native vector types for __builtin_nontemporal_{load,store}.
typedef unsigned nt_uint4  __attribute__((ext_vector_type(4)));
typedef float    nt_float4 __attribute__((ext_vector_type(4)));
typedef float    nt_float2 __attribute__((ext_vector_type(2)));

// ---- workspace layout (bytes) ----
// offsets doubles as the count buffer (scan runs in-place, R0 scheme).
// srows = bf16 rows in VOXEL-SORTED order (replaces rows + ids).
#define WS_OFFSETS 0
#define WS_VR      ((TOTVOX + 4) * 4)                      //  7,077,904
#define WS_SROWS   (WS_VR + TOTPTS * 4 + 16)               // 11,993,120 (32B aligned)
#define WS_SUMS    (WS_SROWS + (size_t)TOTPTS * ROWW * 4)  // 51,314,720
#define WS_NEEDED  ((size_t)(WS_SUMS + 4096))              // ~51.3 MB (well under budget)

// bf16 round-to-nearest-even (inputs finite)
__device__ __forceinline__ unsigned bf16_rtne(float f) {
    unsigned u = __float_as_uint(f);
    return (u + 0x7FFFu + ((u >> 16) & 1u)) >> 16;
}
__device__ __forceinline__ unsigned pack2(float lo, float hi) {
    return bf16_rtne(lo) | (bf16_rtne(hi) << 16);
}

// ============================== fast path ==============================

// SESSION MODEL (R0-R3 measured): the 1.23M scattered lane-atomics cost a
// fixed ~62us wall regardless of address spreading (R2 null) or cache scope
// (R3 null) -> the cost is per-lane CRACK at the CU memory pipe (~35cyc/lane
// x 4800 lanes/CU), paid at issue. It is a floor for this counting-sort
// structure; stop attacking it. This round removes the OTHER big cost: the
// gather's ids->rows dependent random-read chain, by writing rows directly
// in voxel-sorted order at scatter time (gather becomes pure streaming).

// Histogram + per-point (voxel,rank). 4 pts/thread (R1's k_vox, measured
// ~62us). Device-scope atomicAdd on a single count plane -- per the crack
// model, scope/replication don't matter; single plane = smallest memset
// and in-place scan.
__global__ void k_hist(const float* __restrict__ coords,    // [B,3,NPTS]
                       const float* __restrict__ origin,    // [B,3]
                       unsigned*    __restrict__ vr,        // [TOTPTS] packed
                       unsigned*    __restrict__ cnt)       // [TOTVOX] (= offsets buf)
{
    int t = blockIdx.x * blockDim.x + threadIdx.x;
    if (t >= TOTPTS / 4) return;
    int pid = t * 4;
    int b = pid / NPTS;          // NPTS % 4 == 0 -> all four points same batch
    int n = pid - b * NPTS;

    const float* cb = coords + (size_t)b * 3 * NPTS;
    nt_float4 X = __builtin_nontemporal_load((const nt_float4*)(cb + n));
    nt_float4 Y = __builtin_nontemporal_load((const nt_float4*)(cb + NPTS + n));
    nt_float4 Z = __builtin_nontemporal_load((const nt_float4*)(cb + 2 * NPTS + n));
    float ox = origin[b * 3 + 0];
    float oy = origin[b * 3 + 1];
    float oz = origin[b * 3 + 2];

    float xs[4] = {X.x, X.y, X.z, X.w};
    float ys[4] = {Y.x, Y.y, Y.z, Y.w};
    float zs[4] = {Z.x, Z.y, Z.z, Z.w};

    // IEEE f32 division + floorf: must match numpy reference binning exactly.
    int  vv[4];
    bool ib[4];
    #pragma unroll
    for (int k = 0; k < 4; ++k) {
        int ix = (int)floorf((xs[k] - ox) / VOXEL_SIZE);
        int iy = (int)floorf((ys[k] - oy) / VOXEL_SIZE);
        int iz = (int)floorf((zs[k] - oz) / VOXEL_SIZE);
        ib[k] = ((unsigned)ix < GRID_W) & ((unsigned)iy < GRID_L) & ((unsigned)iz < GRID_H);
        vv[k] = b * NVOX + ix * (GRID_L * GRID_H) + iy * GRID_H + iz;
    }
    unsigned ps[4];
    #pragma unroll
    for (int k = 0; k < 4; ++k) {
        unsigned p = 0xFFFFFFFFu;
        if (ib[k]) {
            unsigned r = atomicAdd(&cnt[vv[k]], 1u);
            p = ((unsigned)vv[k] << 10) | (r & 1023u);   // counts <= ~40 here
        }
        ps[k] = p;
    }
    *(uint4*)(vr + pid) = uint4{ps[0], ps[1], ps[2], ps[3]};
}

// Scan level 1, IN-PLACE on the count buffer: per-2048-chunk exclusive
// partials + chunk totals. Also emits the occupancy output plane.
__global__ void k_scan1(unsigned* __restrict__ offsets,   // counts in, partial offsets out
                        unsigned* __restrict__ sums,
                        float*    __restrict__ occ)       // [TOTVOX] in d_out
{
    __shared__ unsigned s[SCAN_TPB];
    int t = threadIdx.x;
    int base = blockIdx.x * SCAN_CHUNK + t * SCAN_EPT;

    uint4 a = ((const uint4*)(offsets + base))[0];
    uint4 c = ((const uint4*)(offsets + base))[1];
    unsigned e[SCAN_EPT] = {a.x, a.y, a.z, a.w, c.x, c.y, c.z, c.w};

    nt_float4 oc0, oc1;
    oc0.x = (e[0] >= MIN_PTS) ? 1.f : 0.f;  oc0.y = (e[1] >= MIN_PTS) ? 1.f : 0.f;
    oc0.z = (e[2] >= MIN_PTS) ? 1.f : 0.f;  oc0.w = (e[3] >= MIN_PTS) ? 1.f : 0.f;
    oc1.x = (e[4] >= MIN_PTS) ? 1.f : 0.f;  oc1.y = (e[5] >= MIN_PTS) ? 1.f : 0.f;
    oc1.z = (e[6] >= MIN_PTS) ? 1.f : 0.f;  oc1.w = (e[7] >= MIN_PTS) ? 1.f : 0.f;
    __builtin_nontemporal_store(oc0, ((nt_float4*)(occ + base)));
    __builtin_nontemporal_store(oc1, ((nt_float4*)(occ + base)) + 1);

    unsigned tot = 0;
    #pragma unroll
    for (int k = 0; k < SCAN_EPT; ++k) { unsigned v = e[k]; e[k] = tot; tot += v; }

    s[t] = tot;
    __syncthreads();
    #pragma unroll
    for (int off = 1; off < SCAN_TPB; off <<= 1) {
        unsigned v = (t >= off) ? s[t - off] : 0u;
        __syncthreads();
        s[t] += v;
        __syncthreads();
    }
    unsigned prefix = s[t] - tot;   // exclusive within chunk
    #pragma unroll
    for (int k = 0; k < SCAN_EPT; ++k) e[k] += prefix;

    ((uint4*)(offsets + base))[0] = uint4{e[0], e[1], e[2], e[3]};
    ((uint4*)(offsets + base))[1] = uint4{e[4], e[5], e[6], e[7]};

    if (t == SCAN_TPB - 1) sums[blockIdx.x] = s[t];
}

// Scan level 2: exclusive scan of the 864 chunk sums (single block).
// Consumers add sums[v >> 11] themselves. sums[SCAN_BLKS] = grand total.
__global__ void k_scan2(unsigned* __restrict__ sums) {
    __shared__ unsigned s[1024];
    int t = threadIdx.x;
    unsigned my = (t < SCAN_BLKS) ? sums[t] : 0u;
    s[t] = my;
    __syncthreads();
    #pragma unroll
    for (int off = 1; off < 1024; off <<= 1) {
        unsigned v = (t >= off) ? s[t - off] : 0u;
        __syncthreads();
        s[t] += v;
        __syncthreads();
    }
    if (t < SCAN_BLKS) sums[t] = s[t] - my;          // exclusive
    if (t == SCAN_BLKS - 1) sums[SCAN_BLKS] = s[t];  // grand total sentinel
}

// Scatter + pack fused: reads attrs with the streaming k_pack access
// pattern (channel-major, 4 consecutive points/thread = coalesced 16B
// lanes), packs bf16 rows in registers, and writes each 32B row DIRECTLY
// to its voxel-sorted position. Replaces the old rows buffer + ids array
// (-78MB of traffic, and downstream gather loses its indirection).
// Random 32B row writes merge in L2 (region 39MB, sorted adjacency).
__global__ void k_scatter_rows(const unsigned* __restrict__ vr,      // [TOTPTS] packed
                               const float*    __restrict__ attrs,   // [B,C,NPTS]
                               const unsigned* __restrict__ offsets, // [TOTVOX]
                               const unsigned* __restrict__ sums,    // [SCAN_BLKS+1]
                               unsigned*       __restrict__ srows)   // [TOTPTS,8] sorted
{
    int t = blockIdx.x * blockDim.x + threadIdx.x;
    if (t >= TOTPTS / 4) return;
    int pid = t * 4;
    int b = pid / NPTS;          // NPTS % 4 == 0 -> same batch
    int n = pid - b * NPTS;

    uint4 P = *(const uint4*)(vr + pid);
    unsigned ps[4] = {P.x, P.y, P.z, P.w};

    // Pack all 4 points' 16 channels to bf16 rows in registers.
    const float* ab = attrs + (size_t)b * CHANS * NPTS + n;
    unsigned w[4][ROWW];
    #pragma unroll
    for (int c = 0; c < CHANS; c += 2) {
        nt_float4 a0 = __builtin_nontemporal_load((const nt_float4*)(ab + (size_t)c * NPTS));
        nt_float4 a1 = __builtin_nontemporal_load((const nt_float4*)(ab + (size_t)(c + 1) * NPTS));
        w[0][c >> 1] = pack2(a0.x, a1.x);
        w[1][c >> 1] = pack2(a0.y, a1.y);
        w[2][c >> 1] = pack2(a0.z, a1.z);
        w[3][c >> 1] = pack2(a0.w, a1.w);
    }

    #pragma unroll
    for (int k = 0; k < 4; ++k) {
        unsigned p = ps[k];
        if (p != 0xFFFFFFFFu) {
            unsigned v   = p >> 10;
            unsigned pos = offsets[v] + sums[v >> 11] + (p & 1023u);
            uint4* d = (uint4*)(srows + (size_t)pos * ROWW);
            d[0] = uint4{w[k][0], w[k][1], w[k][2], w[k][3]};
            d[1] = uint4{w[k][4], w[k][5], w[k][6], w[k][7]};
        }
    }
}

// Gather + finalize: ONE thread per 2 adjacent voxels, all 16 channels.
// Voxel segments are CONTIGUOUS in srows -> pure sequential reads (two
// adjacent rows share a 64B line; nontemporal: each line read exactly
// once). No ids indirection, no dependent random loads. Nontemporal
// float2 output stores.
__global__ void k_gather_seq2(const unsigned* __restrict__ srows,   // [TOTPTS,8] sorted
                              const unsigned* __restrict__ offsets, // [TOTVOX+4]
                              const unsigned* __restrict__ sums,    // [SCAN_BLKS+1]
                              float*          __restrict__ data)    // [B,C,NVOX]
{
    int g = blockIdx.x * blockDim.x + threadIdx.x;
    if (g >= TOTVOX / 2) return;
    int vox0 = g * 2;

    // vox0 % 2 == 0 and chunk size 2048 % 2 == 0 -> vox0, vox0+1 same chunk.
    uint2 O = *(const uint2*)(offsets + vox0);
    unsigned base = sums[vox0 >> 11];
    unsigned s[3];
    s[0] = O.x + base;
    s[1] = O.y + base;
    s[2] = offsets[vox0 + 2] + sums[(vox0 + 2) >> 11];  // sentinels cover end

    float m[2][CHANS];
    #pragma unroll
    for (int q = 0; q < 2; ++q) {
        unsigned k = s[q + 1] - s[q];
        unsigned s0 = s[q];
        if (k >= MIN_PTS) {
            const float ninf = -__builtin_inff();
            #pragma unroll
            for (int c = 0; c < CHANS; ++c) m[q][c] = ninf;
            unsigned j = 0;
            for (; j + 2 <= k; j += 2) {           // 64B contiguous per step
                const nt_uint4* rp = (const nt_uint4*)(srows + (size_t)(s0 + j) * ROWW);
                nt_uint4 l0 = __builtin_nontemporal_load(rp);
                nt_uint4 h0 = __builtin_nontemporal_load(rp + 1);
                nt_uint4 l1 = __builtin_nontemporal_load(rp + 2);
                nt_uint4 h1 = __builtin_nontemporal_load(rp + 3);
                unsigned wa[8] = {l0.x, l0.y, l0.z, l0.w, h0.x, h0.y, h0.z, h0.w};
                unsigned wb[8] = {l1.x, l1.y, l1.z, l1.w, h1.x, h1.y, h1.z, h1.w};
                #pragma unroll
                for (int h = 0; h < 8; ++h) {
                    m[q][2 * h]     = fmaxf(m[q][2 * h],
                                        fmaxf(__uint_as_float(wa[h] << 16),
                                              __uint_as_float(wb[h] << 16)));
                    m[q][2 * h + 1] = fmaxf(m[q][2 * h + 1],
                                        fmaxf(__uint_as_float(wa[h] & 0xFFFF0000u),
                                              __uint_as_float(wb[h] & 0xFFFF0000u)));
                }
            }
            if (j < k) {
                const nt_uint4* rp = (const nt_uint4*)(srows + (size_t)(s0 + j) * ROWW);
                nt_uint4 l0 = __builtin_nontemporal_load(rp);
                nt_uint4 h0 = __builtin_nontemporal_load(rp + 1);
                unsigned wa[8] = {l0.x, l0.y, l0.z, l0.w, h0.x, h0.y, h0.z, h0.w};
                #pragma unroll
                for (int h = 0; h < 8; ++h) {
                    m[q][2 * h]     = fmaxf(m[q][2 * h], __uint_as_float(wa[h] << 16));
                    m[q][2 * h + 1] = fmaxf(m[q][2 * h + 1],
                                            __uint_as_float(wa[h] & 0xFFFF0000u));
                }
            }
            #pragma unroll
            for (int c = 0; c < CHANS; ++c) if (!isfinite(m[q][c])) m[q][c] = 0.f;
        } else {
            #pragma unroll
            for (int c = 0; c < CHANS; ++c) m[q][c] = 0.f;
        }
    }

    int b = vox0 / NVOX;                 // NVOX % 2 == 0
    int v0 = vox0 - b * NVOX;
    float* db = data + (size_t)b * CHANS * NVOX + v0;
    #pragma unroll
    for (int c = 0; c < CHANS; ++c) {
        nt_float2 o = {m[0][c], m[1][c]};
        __builtin_nontemporal_store(o, (nt_float2*)(db + (size_t)c * NVOX));
    }
}

// ============================== fallback path ==============================

__device__ __forceinline__ unsigned flip_f32(float f) {
    unsigned u = __float_as_uint(f);
    unsigned mask = (unsigned)(-(int)(u >> 31)) | 0x80000000u;
    return u ^ mask;
}
__device__ __forceinline__ float unflip_f32(unsigned u) {
    unsigned mask = ((u >> 31) - 1u) | 0x80000000u;
    return __uint_as_float(u ^ mask);
}
#define FLIP_NEG_INF 0x007FFFFFu

__global__ void pv_init(uint4* __restrict__ out) {
    const int DATA4 = BATCH * CHANS * NVOX / 4;
    const int TOT4  = BATCH * (CHANS + 1) * NVOX / 4;
    int i = blockIdx.x * blockDim.x + threadIdx.x;
    if (i < TOT4) {
        unsigned val = (i < DATA4) ? FLIP_NEG_INF : 0u;
        out[i] = uint4{val, val, val, val};
    }
}

__global__ void pv_scatter(const float* __restrict__ coords,
                           const float* __restrict__ attrs,
                           const float* __restrict__ origin,
                           unsigned*    __restrict__ data_u,
                           unsigned*    __restrict__ cnt)
{
    int id = blockIdx.x * blockDim.x + threadIdx.x;
    if (id >= TOTPTS) return;
    int b = id / NPTS;
    int n = id - b * NPTS;
    const float* cb = coords + (size_t)b * 3 * NPTS;
    float x = cb[n], y = cb[NPTS + n], z = cb[2 * NPTS + n];
    float ox = origin[b * 3 + 0], oy = origin[b * 3 + 1], oz = origin[b * 3 + 2];
    int ix = (int)floorf((x - ox) / VOXEL_SIZE);
    int iy = (int)floorf((y - oy) / VOXEL_SIZE);
    int iz = (int)floorf((z - oz) / VOXEL_SIZE);
    if ((unsigned)ix < GRID_W && (unsigned)iy < GRID_L && (unsigned)iz < GRID_H) {
        int flat = ix * (GRID_L * GRID_H) + iy * GRID_H + iz;
        atomicAdd(&cnt[b * NVOX + flat], 1u);
        const float* ab = attrs + (size_t)b * CHANS * NPTS + n;
        unsigned*    db = data_u + (size_t)b * CHANS * NVOX + flat;
        #pragma unroll
        for (int c = 0; c < CHANS; ++c)
            atomicMax(&db[(size_t)c * NVOX], flip_f32(ab[(size_t)c * NPTS]));
    }
}

__global__ void pv_finalize(unsigned* __restrict__ data_u,
                            unsigned* __restrict__ cnt_u)
{
    int id = blockIdx.x * blockDim.x + threadIdx.x;
    if (id >= TOTVOX) return;
    int b = id / NVOX;
    int v = id - b * NVOX;
    unsigned cnt = cnt_u[id];
    bool occ = (cnt >= MIN_PTS);
    ((float*)cnt_u)[id] = occ ? 1.0f : 0.0f;
    unsigned* db = data_u + (size_t)b * CHANS * NVOX + v;
    #pragma unroll
    for (int c = 0; c < CHANS; ++c) {
        float f = unflip_f32(db[(size_t)c * NVOX]);
        ((float*)db)[(size_t)c * NVOX] = (occ && isfinite(f)) ? f : 0.0f;
    }
}

// ============================== launch ==============================

extern "C" void kernel_launch(void* const* d_in, const int* in_sizes, int n_in,
                              void* d_out, int out_size, void* d_ws, size_t ws_size,
                              hipStream_t stream) {
    const float* coords = (const float*)d_in[0];  // [4,3,480,640]
    const float* attrs  = (const float*)d_in[1];  // [4,16,480,640]
    const float* origin = (const float*)d_in[2];  // [4,3]

    float* out = (float*)d_out;
    float* data = out;                                          // [B,C,NVOX]
    float* occ  = out + (size_t)BATCH * CHANS * NVOX;           // [B,NVOX]

    if (ws_size >= WS_NEEDED) {
        char* ws = (char*)d_ws;
        unsigned* offsets = (unsigned*)(ws + WS_OFFSETS);  // counts -> offsets (in-place)
        unsigned* vr      = (unsigned*)(ws + WS_VR);
        unsigned* srows   = (unsigned*)(ws + WS_SROWS);
        unsigned* sums    = (unsigned*)(ws + WS_SUMS);

        // zero counts + the 4 sentinel words past the end
        (void)hipMemsetAsync(offsets, 0, (size_t)(TOTVOX + 4) * 4, stream);
        k_hist<<<(TOTPTS / 4 + 255) / 256, 256, 0, stream>>>(coords, origin, vr, offsets);
        k_scan1<<<SCAN_BLKS, SCAN_TPB, 0, stream>>>(offsets, sums, occ);
        k_scan2<<<1, 1024, 0, stream>>>(sums);
        k_scatter_rows<<<(TOTPTS / 4 + 255) / 256, 256, 0, stream>>>(vr, attrs, offsets,
                                                                     sums, srows);
        k_gather_seq2<<<(TOTVOX / 2 + 255) / 256, 256, 0, stream>>>(srows, offsets,
                                                                    sums, data);
    } else {
        unsigned* data_u = (unsigned*)data;
        unsigned* cnt    = (unsigned*)occ;
        const int TOT4 = BATCH * (CHANS + 1) * NVOX / 4;
        pv_init<<<(TOT4 + 255) / 256, 256, 0, stream>>>((uint4*)d_out);
        pv_scatter<<<(TOTPTS + 255) / 256, 256, 0, stream>>>(coords, attrs, origin, data_u, cnt);
        pv_finalize<<<(TOTVOX + 255) / 256, 256, 0, stream>>>(data_u, cnt);
    }
}

// Round 5
// 310.262 us; speedup vs baseline: 1.0956x; 1.0956x over previous
//
#include <hip/hip_runtime.h>
#include <cstdint>
#include <math.h>

// Problem constants (from reference)
#define GRID_W 96
#define GRID_L 96
#define GRID_H 48
#define NVOX (GRID_W * GRID_L * GRID_H)   // 442368
#define VOXEL_SIZE 0.05f
#define MIN_PTS 10
#define BATCH 4
#define CHANS 16
#define NPTS (480 * 640)                  // 307200 points per batch
#define TOTPTS (BATCH * NPTS)             // 1228800
#define TOTVOX (BATCH * NVOX)             // 1769472

// Scan geometry: 864 blocks x 256 threads x 8 elems = 1769472 exactly.
#define SCAN_BLKS 864
#define SCAN_TPB 256
#define SCAN_EPT 8
#define SCAN_CHUNK (SCAN_TPB * SCAN_EPT)  // 2048

#define ROWW 8   // uint words per bf16 row (16 channels x 2B = 32B)

// Max possible active voxels: TOTPTS / MIN_PTS = 122880.
#define WL_MAX 131072

// Native vector types for __builtin_nontemporal_{load,store}.
typedef unsigned nt_uint4  __attribute__((ext_vector_type(4)));
typedef float    nt_float4 __attribute__((ext_vector_type(4)));
typedef float    nt_float2 __attribute__((ext_vector_type(2)));

// ---- workspace layout (bytes) ----
// offsets doubles as the count buffer (scan runs in-place). 4 sentinel
// words (zeroed) + 1 worklist-counter word follow it.
#define WS_OFFSETS 0
#define WS_VR      ((TOTVOX + 8) * 4)                     //  7,077,920
#define WS_IDS     (WS_VR + TOTPTS * 4)                   // 11,993,120
#define WS_ROWS    (WS_IDS + TOTPTS * 4 + 16)             // 16,908,336 (32B aligned)
#define WS_SUMS    (WS_ROWS + (size_t)TOTPTS * ROWW * 4)  // 56,229,936
#define WS_WL      (WS_SUMS + 4096)
#define WS_NEEDED  ((size_t)(WS_WL + WL_MAX * 4))          // ~56.8 MB (< proven budget)

// bf16 round-to-nearest-even (inputs finite)
__device__ __forceinline__ unsigned bf16_rtne(float f) {
    unsigned u = __float_as_uint(f);
    return (u + 0x7FFFu + ((u >> 16) & 1u)) >> 16;
}
__device__ __forceinline__ unsigned pack2(float lo, float hi) {
    return bf16_rtne(lo) | (bf16_rtne(hi) << 16);
}

// ============================== fast path ==============================

// SESSION MODEL (R0-R4 measured):
//  * 1.23M scattered lane-atomics = fixed ~62us wall; address spreading
//    (R2), scope (R3) both null -> per-lane crack cost at the CU memory
//    pipe, paid at issue. FLOOR; do not attack.
//  * R4: even a fully-sequential gather runs 80us at 23% HBM / 30% occ ->
//    the gather cost is LOAD IMBALANCE: only ~6% of voxels are occupied
//    (points live in a 30x30x30 corner); the empty-voxel sweep wastes 94%
//    of threads and the hot tail (~3 waves/CU) can't hide latency.
//  * Sorted-position row writes (R4 scatter) are worse than point-order
//    writes + L3-resident random reads (R0). Keep R0's layout.
// This round: R0 pipeline verbatim, but gather runs ONLY over a compacted
// worklist of active voxels; empty-voxel zeros come from a memset at fill
// rate (~6.6 TB/s measured on this harness).

// Fused: per-point voxel id + histogram + POINT-ORDER bf16 row packing.
// (R0's measured-best front kernel, 72.5us.)
__global__ void k_hist_pack(const float* __restrict__ coords,   // [B,3,NPTS]
                            const float* __restrict__ attrs,    // [B,C,NPTS]
                            const float* __restrict__ origin,   // [B,3]
                            unsigned*    __restrict__ vr,       // [TOTPTS] packed
                            unsigned*    __restrict__ rows,     // [TOTPTS,8] words, point order
                            unsigned*    __restrict__ cnt)      // [TOTVOX] (= offsets buf)
{
    int t = blockIdx.x * blockDim.x + threadIdx.x;
    if (t >= TOTPTS / 2) return;
    int pid = t * 2;
    int b = pid / NPTS;          // NPTS % 2 == 0 -> both points same batch
    int n = pid - b * NPTS;

    const float* cb = coords + (size_t)b * 3 * NPTS;
    nt_float2 X = __builtin_nontemporal_load((const nt_float2*)(cb + n));
    nt_float2 Y = __builtin_nontemporal_load((const nt_float2*)(cb + NPTS + n));
    nt_float2 Z = __builtin_nontemporal_load((const nt_float2*)(cb + 2 * NPTS + n));
    float ox = origin[b * 3 + 0];
    float oy = origin[b * 3 + 1];
    float oz = origin[b * 3 + 2];

    // Pack both points' 16 channels to bf16 rows (64 B contiguous/thread).
    const float* ab = attrs + (size_t)b * CHANS * NPTS + n;
    unsigned w[2][ROWW];
    #pragma unroll
    for (int c = 0; c < CHANS; c += 2) {
        nt_float2 a0 = __builtin_nontemporal_load((const nt_float2*)(ab + (size_t)c * NPTS));
        nt_float2 a1 = __builtin_nontemporal_load((const nt_float2*)(ab + (size_t)(c + 1) * NPTS));
        w[0][c >> 1] = pack2(a0.x, a1.x);
        w[1][c >> 1] = pack2(a0.y, a1.y);
    }
    uint4* dst = (uint4*)(rows + (size_t)pid * ROWW);
    dst[0] = uint4{w[0][0], w[0][1], w[0][2], w[0][3]};
    dst[1] = uint4{w[0][4], w[0][5], w[0][6], w[0][7]};
    dst[2] = uint4{w[1][0], w[1][1], w[1][2], w[1][3]};
    dst[3] = uint4{w[1][4], w[1][5], w[1][6], w[1][7]};

    // IEEE f32 division + floorf: must match numpy reference binning exactly.
    float xs[2] = {X.x, X.y};
    float ys[2] = {Y.x, Y.y};
    float zs[2] = {Z.x, Z.y};
    unsigned ps[2];
    #pragma unroll
    for (int k = 0; k < 2; ++k) {
        int ix = (int)floorf((xs[k] - ox) / VOXEL_SIZE);
        int iy = (int)floorf((ys[k] - oy) / VOXEL_SIZE);
        int iz = (int)floorf((zs[k] - oz) / VOXEL_SIZE);
        unsigned p = 0xFFFFFFFFu;
        if ((unsigned)ix < GRID_W && (unsigned)iy < GRID_L && (unsigned)iz < GRID_H) {
            int v = b * NVOX + ix * (GRID_L * GRID_H) + iy * GRID_H + iz;
            unsigned r = atomicAdd(&cnt[v], 1u);
            p = ((unsigned)v << 10) | (r & 1023u);
        }
        ps[k] = p;
    }
    *(uint2*)(vr + pid) = uint2{ps[0], ps[1]};
}

// Scan level 1, IN-PLACE on the count buffer: per-2048-chunk exclusive
// partials + chunk totals. Emits occupancy plane AND compacts the ids of
// active voxels (count >= MIN_PTS) into the worklist (one atomicAdd/block).
__global__ void k_scan1(unsigned* __restrict__ offsets,   // counts in, partial offsets out
                        unsigned* __restrict__ sums,
                        float*    __restrict__ occ,       // [TOTVOX] in d_out
                        unsigned* __restrict__ wl,        // [WL_MAX] active voxel ids
                        unsigned* __restrict__ wlcnt)     // [1], pre-zeroed
{
    __shared__ unsigned s[SCAN_TPB];
    __shared__ unsigned bbase;
    int t = threadIdx.x;
    int base = blockIdx.x * SCAN_CHUNK + t * SCAN_EPT;

    uint4 a = ((const uint4*)(offsets + base))[0];
    uint4 c = ((const uint4*)(offsets + base))[1];
    unsigned e[SCAN_EPT] = {a.x, a.y, a.z, a.w, c.x, c.y, c.z, c.w};

    unsigned amask = 0;
    #pragma unroll
    for (int k = 0; k < SCAN_EPT; ++k) amask |= (e[k] >= MIN_PTS) ? (1u << k) : 0u;

    nt_float4 oc0, oc1;
    oc0.x = (amask & 1u)   ? 1.f : 0.f;  oc0.y = (amask & 2u)   ? 1.f : 0.f;
    oc0.z = (amask & 4u)   ? 1.f : 0.f;  oc0.w = (amask & 8u)   ? 1.f : 0.f;
    oc1.x = (amask & 16u)  ? 1.f : 0.f;  oc1.y = (amask & 32u)  ? 1.f : 0.f;
    oc1.z = (amask & 64u)  ? 1.f : 0.f;  oc1.w = (amask & 128u) ? 1.f : 0.f;
    __builtin_nontemporal_store(oc0, ((nt_float4*)(occ + base)));
    __builtin_nontemporal_store(oc1, ((nt_float4*)(occ + base)) + 1);

    unsigned tot = 0;
    #pragma unroll
    for (int k = 0; k < SCAN_EPT; ++k) { unsigned v = e[k]; e[k] = tot; tot += v; }

    s[t] = tot;
    __syncthreads();
    #pragma unroll
    for (int off = 1; off < SCAN_TPB; off <<= 1) {
        unsigned v = (t >= off) ? s[t - off] : 0u;
        __syncthreads();
        s[t] += v;
        __syncthreads();
    }
    unsigned prefix = s[t] - tot;   // exclusive within chunk
    #pragma unroll
    for (int k = 0; k < SCAN_EPT; ++k) e[k] += prefix;

    ((uint4*)(offsets + base))[0] = uint4{e[0], e[1], e[2], e[3]};
    ((uint4*)(offsets + base))[1] = uint4{e[4], e[5], e[6], e[7]};

    if (t == SCAN_TPB - 1) sums[blockIdx.x] = s[t];

    // ---- worklist compaction: second LDS scan over active counts ----
    unsigned acnt = (unsigned)__popc((int)amask);
    __syncthreads();            // protect s[] reuse
    s[t] = acnt;
    __syncthreads();
    #pragma unroll
    for (int off = 1; off < SCAN_TPB; off <<= 1) {
        unsigned v = (t >= off) ? s[t - off] : 0u;
        __syncthreads();
        s[t] += v;
        __syncthreads();
    }
    unsigned apre = s[t] - acnt;    // exclusive within block
    if (t == SCAN_TPB - 1) bbase = atomicAdd(wlcnt, s[t]);
    __syncthreads();
    unsigned wpos = bbase + apre;
    #pragma unroll
    for (int k = 0; k < SCAN_EPT; ++k) {
        if (amask & (1u << k)) wl[wpos++] = (unsigned)(base + k);
    }
}

// Scan level 2: exclusive scan of the 864 chunk sums (single block).
// Consumers add sums[v >> 11] themselves. sums[SCAN_BLKS] = grand total.
__global__ void k_scan2(unsigned* __restrict__ sums) {
    __shared__ unsigned s[1024];
    int t = threadIdx.x;
    unsigned my = (t < SCAN_BLKS) ? sums[t] : 0u;
    s[t] = my;
    __syncthreads();
    #pragma unroll
    for (int off = 1; off < 1024; off <<= 1) {
        unsigned v = (t >= off) ? s[t - off] : 0u;
        __syncthreads();
        s[t] += v;
        __syncthreads();
    }
    if (t < SCAN_BLKS) sums[t] = s[t] - my;          // exclusive
    if (t == SCAN_BLKS - 1) sums[SCAN_BLKS] = s[t];  // grand total sentinel
}

// Scatter point-ids into voxel segments. The random 4 B writes land in a
// 4.9 MB array -> fully absorbed by the 32 MB aggregate L2. No atomics.
__global__ void k_scatter_ids4(const unsigned* __restrict__ vr,      // [TOTPTS] packed
                               const unsigned* __restrict__ offsets, // [TOTVOX]
                               const unsigned* __restrict__ sums,    // [SCAN_BLKS+1]
                               int*            __restrict__ ids)     // [TOTPTS]
{
    int t = blockIdx.x * blockDim.x + threadIdx.x;
    if (t >= TOTPTS / 4) return;
    int pid = t * 4;
    uint4 P = *(const uint4*)(vr + pid);
    unsigned ps[4] = {P.x, P.y, P.z, P.w};
    #pragma unroll
    for (int k = 0; k < 4; ++k) {
        if (ps[k] != 0xFFFFFFFFu) {
            unsigned v = ps[k] >> 10;
            unsigned pos = offsets[v] + sums[v >> 11] + (ps[k] & 1023u);
            ids[pos] = pid + k;
        }
    }
}

// Worklist gather: ONE thread per ACTIVE voxel (grid-stride over ~108K
// entries; count read once). Every thread does real work -> no imbalance
// tail. ids reads: segments of consecutive worklist voxels are adjacent
// (sorted starts) -> coalesced-ish. rows reads: random 32 B in a 39 MB
// L3-resident, just-written region; REGULAR cached loads (R0-proven).
// Output: 16 x 4 B stores into mostly-consecutive voxel runs; empty
// voxels were zeroed by the preceding memset at fill rate.
__global__ void k_gather_wl(const unsigned* __restrict__ rows,    // [TOTPTS,8] point order
                            const int*      __restrict__ ids,     // [TOTPTS]
                            const unsigned* __restrict__ offsets, // [TOTVOX+4]
                            const unsigned* __restrict__ sums,    // [SCAN_BLKS+1]
                            const unsigned* __restrict__ wl,      // [WL_MAX]
                            const unsigned* __restrict__ wlcnt,   // [1]
                            float*          __restrict__ data)    // [B,C,NVOX]
{
    unsigned nwl = *wlcnt;
    for (unsigned i = blockIdx.x * blockDim.x + threadIdx.x; i < nwl;
         i += gridDim.x * blockDim.x) {
        unsigned v  = wl[i];
        unsigned s0 = offsets[v] + sums[v >> 11];
        unsigned s1 = offsets[v + 1] + sums[(v + 1) >> 11];  // sentinels cover end
        unsigned k  = s1 - s0;                               // >= MIN_PTS by construction

        const float ninf = -__builtin_inff();
        float m[CHANS];
        #pragma unroll
        for (int c = 0; c < CHANS; ++c) m[c] = ninf;

        unsigned j = 0;
        for (; j + 2 <= k; j += 2) {           // unroll x2 for MLP
            int p0 = ids[s0 + j];
            int p1 = ids[s0 + j + 1];
            const uint4* r0p = (const uint4*)(rows + (size_t)p0 * ROWW);
            const uint4* r1p = (const uint4*)(rows + (size_t)p1 * ROWW);
            uint4 l0 = r0p[0], h0 = r0p[1];
            uint4 l1 = r1p[0], h1 = r1p[1];
            unsigned wa[8] = {l0.x, l0.y, l0.z, l0.w, h0.x, h0.y, h0.z, h0.w};
            unsigned wb[8] = {l1.x, l1.y, l1.z, l1.w, h1.x, h1.y, h1.z, h1.w};
            #pragma unroll
            for (int h = 0; h < 8; ++h) {
                m[2 * h]     = fmaxf(m[2 * h],
                                 fmaxf(__uint_as_float(wa[h] << 16),
                                       __uint_as_float(wb[h] << 16)));
                m[2 * h + 1] = fmaxf(m[2 * h + 1],
                                 fmaxf(__uint_as_float(wa[h] & 0xFFFF0000u),
                                       __uint_as_float(wb[h] & 0xFFFF0000u)));
            }
        }
        if (j < k) {
            int p0 = ids[s0 + j];
            const uint4* r0p = (const uint4*)(rows + (size_t)p0 * ROWW);
            uint4 l0 = r0p[0], h0 = r0p[1];
            unsigned wa[8] = {l0.x, l0.y, l0.z, l0.w, h0.x, h0.y, h0.z, h0.w};
            #pragma unroll
            for (int h = 0; h < 8; ++h) {
                m[2 * h]     = fmaxf(m[2 * h], __uint_as_float(wa[h] << 16));
                m[2 * h + 1] = fmaxf(m[2 * h + 1],
                                     __uint_as_float(wa[h] & 0xFFFF0000u));
            }
        }

        unsigned b  = v / NVOX;
        unsigned v0 = v - b * NVOX;
        float* db = data + (size_t)b * CHANS * NVOX + v0;
        #pragma unroll
        for (int c = 0; c < CHANS; ++c) {
            float f = m[c];
            db[(size_t)c * NVOX] = isfinite(f) ? f : 0.f;
        }
    }
}

// ============================== fallback path ==============================

__device__ __forceinline__ unsigned flip_f32(float f) {
    unsigned u = __float_as_uint(f);
    unsigned mask = (unsigned)(-(int)(u >> 31)) | 0x80000000u;
    return u ^ mask;
}
__device__ __forceinline__ float unflip_f32(unsigned u) {
    unsigned mask = ((u >> 31) - 1u) | 0x80000000u;
    return __uint_as_float(u ^ mask);
}
#define FLIP_NEG_INF 0x007FFFFFu

__global__ void pv_init(uint4* __restrict__ out) {
    const int DATA4 = BATCH * CHANS * NVOX / 4;
    const int TOT4  = BATCH * (CHANS + 1) * NVOX / 4;
    int i = blockIdx.x * blockDim.x + threadIdx.x;
    if (i < TOT4) {
        unsigned val = (i < DATA4) ? FLIP_NEG_INF : 0u;
        out[i] = uint4{val, val, val, val};
    }
}

__global__ void pv_scatter(const float* __restrict__ coords,
                           const float* __restrict__ attrs,
                           const float* __restrict__ origin,
                           unsigned*    __restrict__ data_u,
                           unsigned*    __restrict__ cnt)
{
    int id = blockIdx.x * blockDim.x + threadIdx.x;
    if (id >= TOTPTS) return;
    int b = id / NPTS;
    int n = id - b * NPTS;
    const float* cb = coords + (size_t)b * 3 * NPTS;
    float x = cb[n], y = cb[NPTS + n], z = cb[2 * NPTS + n];
    float ox = origin[b * 3 + 0], oy = origin[b * 3 + 1], oz = origin[b * 3 + 2];
    int ix = (int)floorf((x - ox) / VOXEL_SIZE);
    int iy = (int)floorf((y - oy) / VOXEL_SIZE);
    int iz = (int)floorf((z - oz) / VOXEL_SIZE);
    if ((unsigned)ix < GRID_W && (unsigned)iy < GRID_L && (unsigned)iz < GRID_H) {
        int flat = ix * (GRID_L * GRID_H) + iy * GRID_H + iz;
        atomicAdd(&cnt[b * NVOX + flat], 1u);
        const float* ab = attrs + (size_t)b * CHANS * NPTS + n;
        unsigned*    db = data_u + (size_t)b * CHANS * NVOX + flat;
        #pragma unroll
        for (int c = 0; c < CHANS; ++c)
            atomicMax(&db[(size_t)c * NVOX], flip_f32(ab[(size_t)c * NPTS]));
    }
}

__global__ void pv_finalize(unsigned* __restrict__ data_u,
                            unsigned* __restrict__ cnt_u)
{
    int id = blockIdx.x * blockDim.x + threadIdx.x;
    if (id >= TOTVOX) return;
    int b = id / NVOX;
    int v = id - b * NVOX;
    unsigned cnt = cnt_u[id];
    bool occ = (cnt >= MIN_PTS);
    ((float*)cnt_u)[id] = occ ? 1.0f : 0.0f;
    unsigned* db = data_u + (size_t)b * CHANS * NVOX + v;
    #pragma unroll
    for (int c = 0; c < CHANS; ++c) {
        float f = unflip_f32(db[(size_t)c * NVOX]);
        ((float*)db)[(size_t)c * NVOX] = (occ && isfinite(f)) ? f : 0.0f;
    }
}

// ============================== launch ==============================

extern "C" void kernel_launch(void* const* d_in, const int* in_sizes, int n_in,
                              void* d_out, int out_size, void* d_ws, size_t ws_size,
                              hipStream_t stream) {
    const float* coords = (const float*)d_in[0];  // [4,3,480,640]
    const float* attrs  = (const float*)d_in[1];  // [4,16,480,640]
    const float* origin = (const float*)d_in[2];  // [4,3]

    float* out = (float*)d_out;
    float* data = out;                                          // [B,C,NVOX]
    float* occ  = out + (size_t)BATCH * CHANS * NVOX;           // [B,NVOX]

    if (ws_size >= WS_NEEDED) {
        char* ws = (char*)d_ws;
        unsigned* offsets = (unsigned*)(ws + WS_OFFSETS);  // counts -> offsets (in-place)
        unsigned* wlcnt   = offsets + TOTVOX + 4;          // counter word (zeroed below)
        unsigned* vr      = (unsigned*)(ws + WS_VR);
        int*      ids     = (int*)(ws + WS_IDS);
        unsigned* rows    = (unsigned*)(ws + WS_ROWS);
        unsigned* sums    = (unsigned*)(ws + WS_SUMS);
        unsigned* wl      = (unsigned*)(ws + WS_WL);

        // zero counts + 4 sentinel words + worklist counter
        (void)hipMemsetAsync(offsets, 0, (size_t)(TOTVOX + 8) * 4, stream);
        // zero the data output plane (113 MB at fill rate ~6.6 TB/s):
        // empty/below-threshold voxels get their zeros here, not in gather.
        (void)hipMemsetAsync(data, 0, (size_t)BATCH * CHANS * NVOX * 4, stream);
        k_hist_pack<<<(TOTPTS / 2 + 255) / 256, 256, 0, stream>>>(coords, attrs, origin,
                                                                  vr, rows, offsets);
        k_scan1<<<SCAN_BLKS, SCAN_TPB, 0, stream>>>(offsets, sums, occ, wl, wlcnt);
        k_scan2<<<1, 1024, 0, stream>>>(sums);
        k_scatter_ids4<<<(TOTPTS / 4 + 255) / 256, 256, 0, stream>>>(vr, offsets, sums, ids);
        k_gather_wl<<<512, 256, 0, stream>>>(rows, ids, offsets, sums, wl, wlcnt, data);
    } else {
        unsigned* data_u = (unsigned*)data;
        unsigned* cnt    = (unsigned*)occ;
        const int TOT4 = BATCH * (CHANS + 1) * NVOX / 4;
        pv_init<<<(TOT4 + 255) / 256, 256, 0, stream>>>((uint4*)d_out);
        pv_scatter<<<(TOTPTS + 255) / 256, 256, 0, stream>>>(coords, attrs, origin, data_u, cnt);
        pv_finalize<<<(TOTVOX + 255) / 256, 256, 0, stream>>>(data_u, cnt);
    }
}

// Round 6
// 284.413 us; speedup vs baseline: 1.1952x; 1.0909x over previous
//
#include <hip/hip_runtime.h>
#include <cstdint>
#include <math.h>

// Problem constants (from reference)
#define GRID_W 96
#define GRID_L 96
#define GRID_H 48
#define NVOX (GRID_W * GRID_L * GRID_H)   // 442368
#define VOXEL_SIZE 0.05f
#define MIN_PTS 10
#define BATCH 4
#define CHANS 16
#define NPTS (480 * 640)                  // 307200 points per batch
#define TOTPTS (BATCH * NPTS)             // 1228800
#define TOTVOX (BATCH * NVOX)             // 1769472

// Scan geometry: 864 blocks x 256 threads x 8 elems = 1769472 exactly.
#define SCAN_BLKS 864
#define SCAN_TPB 256
#define SCAN_EPT 8
#define SCAN_CHUNK (SCAN_TPB * SCAN_EPT)  // 2048

#define ROWW 8   // uint words per bf16 row (16 channels x 2B = 32B)

// Native vector types for __builtin_nontemporal_{load,store}.
typedef unsigned nt_uint4  __attribute__((ext_vector_type(4)));
typedef float    nt_float4 __attribute__((ext_vector_type(4)));
typedef float    nt_float2 __attribute__((ext_vector_type(2)));

// ---- workspace layout (bytes) ----
// offsets doubles as the count buffer (scan runs in-place).
#define WS_OFFSETS 0
#define WS_VR      ((TOTVOX + 4) * 4)                     //  7,077,904
#define WS_IDS     (WS_VR + TOTPTS * 4)                   // 11,993,104
#define WS_ROWS    (WS_IDS + TOTPTS * 4 + 16)             // 16,908,320 (32B aligned)
#define WS_SUMS    (WS_ROWS + (size_t)TOTPTS * ROWW * 4)  // 56,229,920
#define WS_NEEDED  ((size_t)(WS_SUMS + 4096))             // ~56.2 MB (< proven 90.6 MB budget)

// SESSION MODEL (R0-R5, measured):
//  * dur_us includes ~150us of harness-side 481MB poison fills per
//    iteration (76-86% HBM peak, memory-bound, uncontrollable).
//  * The 1.23M scattered lane-atomics in k_hist_pack are a ~62us wall:
//    address spreading (R2), cache scope (R3), and kernel splitting (R1)
//    all null/regressed -> per-lane crack cost at the CU memory pipe,
//    paid at issue. Thread-fusion with the streaming pack (this kernel)
//    is the best measured overlap (72.5us total vs 62+22 split).
//  * Gather alternatives: sorted-row scatter (R4) and active-voxel
//    worklist + memset zeros (R5) both regressed/null -> the full-sweep
//    gather (~45us) is latency-bound on L3-resident row reads, not
//    imbalance-bound; its zero-writes ride along nearly free.
//  * This file is the empirical optimum of the pipeline family
//    (285.9-287.4us across independent benches).

// bf16 round-to-nearest-even (inputs finite)
__device__ __forceinline__ unsigned bf16_rtne(float f) {
    unsigned u = __float_as_uint(f);
    return (u + 0x7FFFu + ((u >> 16) & 1u)) >> 16;
}
__device__ __forceinline__ unsigned pack2(float lo, float hi) {
    return bf16_rtne(lo) | (bf16_rtne(hi) << 16);
}

// ============================== fast path ==============================

// Fused: per-point voxel id + histogram + POINT-ORDER bf16 row packing.
// TWO points per thread: the thread's rows write is a full 64 B line of
// REGULAR stores (L2 write-combines -> no NT 16B-granule amplification).
// Input streams (coords/attrs) use nontemporal LOADS: single-use, evict-
// first, keeping L2 room for the hot ~430 KB cnt atomic working set.
__global__ void k_hist_pack(const float* __restrict__ coords,   // [B,3,NPTS]
                            const float* __restrict__ attrs,    // [B,C,NPTS]
                            const float* __restrict__ origin,   // [B,3]
                            unsigned*    __restrict__ vr,       // [TOTPTS] packed
                            unsigned*    __restrict__ rows,     // [TOTPTS,8] words, point order
                            unsigned*    __restrict__ cnt)      // [TOTVOX] (= offsets buf)
{
    int t = blockIdx.x * blockDim.x + threadIdx.x;
    if (t >= TOTPTS / 2) return;
    int pid = t * 2;
    int b = pid / NPTS;          // NPTS % 2 == 0 -> both points same batch
    int n = pid - b * NPTS;

    const float* cb = coords + (size_t)b * 3 * NPTS;
    nt_float2 X = __builtin_nontemporal_load((const nt_float2*)(cb + n));
    nt_float2 Y = __builtin_nontemporal_load((const nt_float2*)(cb + NPTS + n));
    nt_float2 Z = __builtin_nontemporal_load((const nt_float2*)(cb + 2 * NPTS + n));
    float ox = origin[b * 3 + 0];
    float oy = origin[b * 3 + 1];
    float oz = origin[b * 3 + 2];

    // Pack both points' 16 channels to bf16 rows (64 B contiguous/thread).
    const float* ab = attrs + (size_t)b * CHANS * NPTS + n;
    unsigned w[2][ROWW];
    #pragma unroll
    for (int c = 0; c < CHANS; c += 2) {
        nt_float2 a0 = __builtin_nontemporal_load((const nt_float2*)(ab + (size_t)c * NPTS));
        nt_float2 a1 = __builtin_nontemporal_load((const nt_float2*)(ab + (size_t)(c + 1) * NPTS));
        w[0][c >> 1] = pack2(a0.x, a1.x);
        w[1][c >> 1] = pack2(a0.y, a1.y);
    }
    uint4* dst = (uint4*)(rows + (size_t)pid * ROWW);
    dst[0] = uint4{w[0][0], w[0][1], w[0][2], w[0][3]};
    dst[1] = uint4{w[0][4], w[0][5], w[0][6], w[0][7]};
    dst[2] = uint4{w[1][0], w[1][1], w[1][2], w[1][3]};
    dst[3] = uint4{w[1][4], w[1][5], w[1][6], w[1][7]};

    // IEEE f32 division + floorf: must match numpy reference binning exactly.
    float xs[2] = {X.x, X.y};
    float ys[2] = {Y.x, Y.y};
    float zs[2] = {Z.x, Z.y};
    unsigned ps[2];
    #pragma unroll
    for (int k = 0; k < 2; ++k) {
        int ix = (int)floorf((xs[k] - ox) / VOXEL_SIZE);
        int iy = (int)floorf((ys[k] - oy) / VOXEL_SIZE);
        int iz = (int)floorf((zs[k] - oz) / VOXEL_SIZE);
        unsigned p = 0xFFFFFFFFu;
        if ((unsigned)ix < GRID_W && (unsigned)iy < GRID_L && (unsigned)iz < GRID_H) {
            int v = b * NVOX + ix * (GRID_L * GRID_H) + iy * GRID_H + iz;
            unsigned r = atomicAdd(&cnt[v], 1u);
            p = ((unsigned)v << 10) | (r & 1023u);
        }
        ps[k] = p;
    }
    *(uint2*)(vr + pid) = uint2{ps[0], ps[1]};
}

// Scan level 1, IN-PLACE on the count buffer: per-2048-chunk exclusive
// partials + chunk totals. Also emits the occupancy output plane.
__global__ void k_scan1(unsigned* __restrict__ offsets,   // counts in, partial offsets out
                        unsigned* __restrict__ sums,
                        float*    __restrict__ occ)       // [TOTVOX] in d_out
{
    __shared__ unsigned s[SCAN_TPB];
    int t = threadIdx.x;
    int base = blockIdx.x * SCAN_CHUNK + t * SCAN_EPT;

    uint4 a = ((const uint4*)(offsets + base))[0];
    uint4 c = ((const uint4*)(offsets + base))[1];
    unsigned e[SCAN_EPT] = {a.x, a.y, a.z, a.w, c.x, c.y, c.z, c.w};

    nt_float4 oc0, oc1;
    oc0.x = (e[0] >= MIN_PTS) ? 1.f : 0.f;  oc0.y = (e[1] >= MIN_PTS) ? 1.f : 0.f;
    oc0.z = (e[2] >= MIN_PTS) ? 1.f : 0.f;  oc0.w = (e[3] >= MIN_PTS) ? 1.f : 0.f;
    oc1.x = (e[4] >= MIN_PTS) ? 1.f : 0.f;  oc1.y = (e[5] >= MIN_PTS) ? 1.f : 0.f;
    oc1.z = (e[6] >= MIN_PTS) ? 1.f : 0.f;  oc1.w = (e[7] >= MIN_PTS) ? 1.f : 0.f;
    __builtin_nontemporal_store(oc0, ((nt_float4*)(occ + base)));
    __builtin_nontemporal_store(oc1, ((nt_float4*)(occ + base)) + 1);

    unsigned tot = 0;
    #pragma unroll
    for (int k = 0; k < SCAN_EPT; ++k) { unsigned v = e[k]; e[k] = tot; tot += v; }

    s[t] = tot;
    __syncthreads();
    #pragma unroll
    for (int off = 1; off < SCAN_TPB; off <<= 1) {
        unsigned v = (t >= off) ? s[t - off] : 0u;
        __syncthreads();
        s[t] += v;
        __syncthreads();
    }
    unsigned prefix = s[t] - tot;   // exclusive within chunk
    #pragma unroll
    for (int k = 0; k < SCAN_EPT; ++k) e[k] += prefix;

    ((uint4*)(offsets + base))[0] = uint4{e[0], e[1], e[2], e[3]};
    ((uint4*)(offsets + base))[1] = uint4{e[4], e[5], e[6], e[7]};

    if (t == SCAN_TPB - 1) sums[blockIdx.x] = s[t];
}

// Scan level 2: exclusive scan of the 864 chunk sums (single block).
// Consumers add sums[v >> 11] themselves. sums[SCAN_BLKS] = grand total.
__global__ void k_scan2(unsigned* __restrict__ sums) {
    __shared__ unsigned s[1024];
    int t = threadIdx.x;
    unsigned my = (t < SCAN_BLKS) ? sums[t] : 0u;
    s[t] = my;
    __syncthreads();
    #pragma unroll
    for (int off = 1; off < 1024; off <<= 1) {
        unsigned v = (t >= off) ? s[t - off] : 0u;
        __syncthreads();
        s[t] += v;
        __syncthreads();
    }
    if (t < SCAN_BLKS) sums[t] = s[t] - my;          // exclusive
    if (t == SCAN_BLKS - 1) sums[SCAN_BLKS] = s[t];  // grand total sentinel
}

// Scatter point-ids into voxel segments. The random 4 B writes land in a
// 4.9 MB array -> fully absorbed by the 32 MB aggregate L2. No atomics.
__global__ void k_scatter_ids4(const unsigned* __restrict__ vr,      // [TOTPTS] packed
                               const unsigned* __restrict__ offsets, // [TOTVOX]
                               const unsigned* __restrict__ sums,    // [SCAN_BLKS+1]
                               int*            __restrict__ ids)     // [TOTPTS]
{
    int t = blockIdx.x * blockDim.x + threadIdx.x;
    if (t >= TOTPTS / 4) return;
    int pid = t * 4;
    uint4 P = *(const uint4*)(vr + pid);
    unsigned ps[4] = {P.x, P.y, P.z, P.w};
    #pragma unroll
    for (int k = 0; k < 4; ++k) {
        if (ps[k] != 0xFFFFFFFFu) {
            unsigned v = ps[k] >> 10;
            unsigned pos = offsets[v] + sums[v >> 11] + (ps[k] & 1023u);
            ids[pos] = pid + k;
        }
    }
}

// Gather + finalize: ONE thread per 2 adjacent voxels, all 16 channels.
// Sequential ids reads; random 32 B row reads use REGULAR cached loads
// (the 64 B line holding two adjacent rows is usually re-hit -> caching
// halves fetch vs NT; NT-load experiment: FETCH 40->67 MB, dur +25 us).
// j-loop unrolled x2 (4 row-loads outstanding). Nontemporal float2
// output stores only (full-line dirty per wave, single-use).
__global__ void k_gather_ind2(const unsigned* __restrict__ rows,    // [TOTPTS,8] point order
                              const int*      __restrict__ ids,     // [TOTPTS]
                              const unsigned* __restrict__ offsets, // [TOTVOX+4]
                              const unsigned* __restrict__ sums,    // [SCAN_BLKS+1]
                              float*          __restrict__ data)    // [B,C,NVOX]
{
    int g = blockIdx.x * blockDim.x + threadIdx.x;
    if (g >= TOTVOX / 2) return;
    int vox0 = g * 2;

    // vox0 % 2 == 0 and chunk size 2048 % 2 == 0 -> vox0, vox0+1 same chunk.
    uint2 O = *(const uint2*)(offsets + vox0);
    unsigned base = sums[vox0 >> 11];
    unsigned s[3];
    s[0] = O.x + base;
    s[1] = O.y + base;
    s[2] = offsets[vox0 + 2] + sums[(vox0 + 2) >> 11];  // sentinels cover end

    float m[2][CHANS];
    #pragma unroll
    for (int q = 0; q < 2; ++q) {
        unsigned k = s[q + 1] - s[q];
        unsigned s0 = s[q];
        if (k >= MIN_PTS) {
            const float ninf = -__builtin_inff();
            #pragma unroll
            for (int c = 0; c < CHANS; ++c) m[q][c] = ninf;
            unsigned j = 0;
            for (; j + 2 <= k; j += 2) {           // unroll x2 for MLP
                int p0 = ids[s0 + j];
                int p1 = ids[s0 + j + 1];
                const uint4* r0p = (const uint4*)(rows + (size_t)p0 * ROWW);
                const uint4* r1p = (const uint4*)(rows + (size_t)p1 * ROWW);
                uint4 l0 = r0p[0], h0 = r0p[1];
                uint4 l1 = r1p[0], h1 = r1p[1];
                unsigned wa[8] = {l0.x, l0.y, l0.z, l0.w, h0.x, h0.y, h0.z, h0.w};
                unsigned wb[8] = {l1.x, l1.y, l1.z, l1.w, h1.x, h1.y, h1.z, h1.w};
                #pragma unroll
                for (int h = 0; h < 8; ++h) {
                    m[q][2 * h]     = fmaxf(m[q][2 * h],
                                        fmaxf(__uint_as_float(wa[h] << 16),
                                              __uint_as_float(wb[h] << 16)));
                    m[q][2 * h + 1] = fmaxf(m[q][2 * h + 1],
                                        fmaxf(__uint_as_float(wa[h] & 0xFFFF0000u),
                                              __uint_as_float(wb[h] & 0xFFFF0000u)));
                }
            }
            if (j < k) {
                int p0 = ids[s0 + j];
                const uint4* r0p = (const uint4*)(rows + (size_t)p0 * ROWW);
                uint4 l0 = r0p[0], h0 = r0p[1];
                unsigned wa[8] = {l0.x, l0.y, l0.z, l0.w, h0.x, h0.y, h0.z, h0.w};
                #pragma unroll
                for (int h = 0; h < 8; ++h) {
                    m[q][2 * h]     = fmaxf(m[q][2 * h], __uint_as_float(wa[h] << 16));
                    m[q][2 * h + 1] = fmaxf(m[q][2 * h + 1],
                                            __uint_as_float(wa[h] & 0xFFFF0000u));
                }
            }
            #pragma unroll
            for (int c = 0; c < CHANS; ++c) if (!isfinite(m[q][c])) m[q][c] = 0.f;
        } else {
            #pragma unroll
            for (int c = 0; c < CHANS; ++c) m[q][c] = 0.f;
        }
    }

    int b = vox0 / NVOX;                 // NVOX % 2 == 0
    int v0 = vox0 - b * NVOX;
    float* db = data + (size_t)b * CHANS * NVOX + v0;
    #pragma unroll
    for (int c = 0; c < CHANS; ++c) {
        nt_float2 o = {m[0][c], m[1][c]};
        __builtin_nontemporal_store(o, (nt_float2*)(db + (size_t)c * NVOX));
    }
}

// ============================== fallback path ==============================

__device__ __forceinline__ unsigned flip_f32(float f) {
    unsigned u = __float_as_uint(f);
    unsigned mask = (unsigned)(-(int)(u >> 31)) | 0x80000000u;
    return u ^ mask;
}
__device__ __forceinline__ float unflip_f32(unsigned u) {
    unsigned mask = ((u >> 31) - 1u) | 0x80000000u;
    return __uint_as_float(u ^ mask);
}
#define FLIP_NEG_INF 0x007FFFFFu

__global__ void pv_init(uint4* __restrict__ out) {
    const int DATA4 = BATCH * CHANS * NVOX / 4;
    const int TOT4  = BATCH * (CHANS + 1) * NVOX / 4;
    int i = blockIdx.x * blockDim.x + threadIdx.x;
    if (i < TOT4) {
        unsigned val = (i < DATA4) ? FLIP_NEG_INF : 0u;
        out[i] = uint4{val, val, val, val};
    }
}

__global__ void pv_scatter(const float* __restrict__ coords,
                           const float* __restrict__ attrs,
                           const float* __restrict__ origin,
                           unsigned*    __restrict__ data_u,
                           unsigned*    __restrict__ cnt)
{
    int id = blockIdx.x * blockDim.x + threadIdx.x;
    if (id >= TOTPTS) return;
    int b = id / NPTS;
    int n = id - b * NPTS;
    const float* cb = coords + (size_t)b * 3 * NPTS;
    float x = cb[n], y = cb[NPTS + n], z = cb[2 * NPTS + n];
    float ox = origin[b * 3 + 0], oy = origin[b * 3 + 1], oz = origin[b * 3 + 2];
    int ix = (int)floorf((x - ox) / VOXEL_SIZE);
    int iy = (int)floorf((y - oy) / VOXEL_SIZE);
    int iz = (int)floorf((z - oz) / VOXEL_SIZE);
    if ((unsigned)ix < GRID_W && (unsigned)iy < GRID_L && (unsigned)iz < GRID_H) {
        int flat = ix * (GRID_L * GRID_H) + iy * GRID_H + iz;
        atomicAdd(&cnt[b * NVOX + flat], 1u);
        const float* ab = attrs + (size_t)b * CHANS * NPTS + n;
        unsigned*    db = data_u + (size_t)b * CHANS * NVOX + flat;
        #pragma unroll
        for (int c = 0; c < CHANS; ++c)
            atomicMax(&db[(size_t)c * NVOX], flip_f32(ab[(size_t)c * NPTS]));
    }
}

__global__ void pv_finalize(unsigned* __restrict__ data_u,
                            unsigned* __restrict__ cnt_u)
{
    int id = blockIdx.x * blockDim.x + threadIdx.x;
    if (id >= TOTVOX) return;
    int b = id / NVOX;
    int v = id - b * NVOX;
    unsigned cnt = cnt_u[id];
    bool occ = (cnt >= MIN_PTS);
    ((float*)cnt_u)[id] = occ ? 1.0f : 0.0f;
    unsigned* db = data_u + (size_t)b * CHANS * NVOX + v;
    #pragma unroll
    for (int c = 0; c < CHANS; ++c) {
        float f = unflip_f32(db[(size_t)c * NVOX]);
        ((float*)db)[(size_t)c * NVOX] = (occ && isfinite(f)) ? f : 0.0f;
    }
}

// ============================== launch ==============================

extern "C" void kernel_launch(void* const* d_in, const int* in_sizes, int n_in,
                              void* d_out, int out_size, void* d_ws, size_t ws_size,
                              hipStream_t stream) {
    const float* coords = (const float*)d_in[0];  // [4,3,480,640]
    const float* attrs  = (const float*)d_in[1];  // [4,16,480,640]
    const float* origin = (const float*)d_in[2];  // [4,3]

    float* out = (float*)d_out;
    float* data = out;                                          // [B,C,NVOX]
    float* occ  = out + (size_t)BATCH * CHANS * NVOX;           // [B,NVOX]

    if (ws_size >= WS_NEEDED) {
        char* ws = (char*)d_ws;
        unsigned* offsets = (unsigned*)(ws + WS_OFFSETS);  // counts -> offsets (in-place)
        unsigned* vr      = (unsigned*)(ws + WS_VR);
        int*      ids     = (int*)(ws + WS_IDS);
        unsigned* rows    = (unsigned*)(ws + WS_ROWS);
        unsigned* sums    = (unsigned*)(ws + WS_SUMS);

        // zero counts + the 4 sentinel words past the end
        (void)hipMemsetAsync(offsets, 0, (size_t)(TOTVOX + 4) * 4, stream);
        k_hist_pack<<<(TOTPTS / 2 + 255) / 256, 256, 0, stream>>>(coords, attrs, origin,
                                                                  vr, rows, offsets);
        k_scan1<<<SCAN_BLKS, SCAN_TPB, 0, stream>>>(offsets, sums, occ);
        k_scan2<<<1, 1024, 0, stream>>>(sums);
        k_scatter_ids4<<<(TOTPTS / 4 + 255) / 256, 256, 0, stream>>>(vr, offsets, sums, ids);
        k_gather_ind2<<<(TOTVOX / 2 + 255) / 256, 256, 0, stream>>>(rows, ids, offsets, sums, data);
    } else {
        unsigned* data_u = (unsigned*)data;
        unsigned* cnt    = (unsigned*)occ;
        const int TOT4 = BATCH * (CHANS + 1) * NVOX / 4;
        pv_init<<<(TOT4 + 255) / 256, 256, 0, stream>>>((uint4*)d_out);
        pv_scatter<<<(TOTPTS + 255) / 256, 256, 0, stream>>>(coords, attrs, origin, data_u, cnt);
        pv_finalize<<<(TOTVOX + 255) / 256, 256, 0, stream>>>(data_u, cnt);
    }
}